// Round 1
// baseline (1706.861 us; speedup 1.0000x reference)
//
#include <hip/hip_runtime.h>
#include <math.h>

#define B_    32
#define H_    128
#define C_    512
#define R_    64
#define S_    4096
#define NS_   8
#define D_    576      // C_ + R_
#define HALF_ 32
#define HT    16       // heads per block
#define KB    16       // kv positions per chunk
#define PITCH 580      // padded LDS row pitch in floats (580*4 B, 16B-aligned, 580%32=4)

// ---------------- RoPE kernels (modify inputs in place; harness restores d_in
// from pristine before every launch, so this is idempotent per launch) --------

__global__ __launch_bounds__(256)
void rope_q_kernel(float* __restrict__ q, const float* __restrict__ cache,
                   const int* __restrict__ positions) {
    int t = blockIdx.x * 256 + threadIdx.x;
    if (t >= B_ * H_ * HALF_) return;
    int i = t & (HALF_ - 1);
    int h = (t >> 5) & (H_ - 1);
    int b = t >> 12;
    int pos = positions[b];
    float c = cache[pos * R_ + i];
    float s = cache[pos * R_ + HALF_ + i];
    float* qp = q + (size_t)(b * H_ + h) * D_ + C_;
    float lo = qp[i], hi = qp[i + HALF_];
    qp[i]         = lo * c - hi * s;
    qp[i + HALF_] = hi * c + lo * s;
}

__global__ __launch_bounds__(256)
void rope_k_kernel(float* __restrict__ kbuf, const float* __restrict__ cache,
                   const int* __restrict__ positions, const int* __restrict__ indptr,
                   const int* __restrict__ indices, float* __restrict__ out_tail) {
    int t = blockIdx.x * 256 + threadIdx.x;
    if (t >= B_ * HALF_) return;
    int i = t & (HALF_ - 1);
    int b = t >> 5;
    int seq = indptr[b + 1] - indptr[b];
    int row = indices[b * S_ + seq - 1];
    int pos = positions[b];
    float c = cache[pos * R_ + i];
    float s = cache[pos * R_ + HALF_ + i];
    float* kp = kbuf + (size_t)row * D_ + C_;
    float lo = kp[i], hi = kp[i + HALF_];
    float nlo = lo * c - hi * s;
    float nhi = hi * c + lo * s;
    kp[i] = nlo; kp[i + HALF_] = nhi;
    out_tail[b * R_ + i]         = nlo;
    out_tail[b * R_ + HALF_ + i] = nhi;
}

__global__ void zero_tail_kernel(float* p) { if (threadIdx.x == 0) p[0] = 0.f; }

// ---------------- fused split attention -------------------------------------

__global__ __launch_bounds__(256, 2)
void mla_attn_kernel(const float* __restrict__ q, const float* __restrict__ kbuf,
                     const float* __restrict__ vbuf, const int* __restrict__ indptr,
                     const int* __restrict__ indices, float* __restrict__ out) {
    __shared__ float q_s[HT * PITCH];      // 37120 B
    __shared__ float k_s[KB * PITCH];      // 37120 B
    __shared__ float s_part[4 * HT * KB];  // 4096 B  [wave][h*KB+j]
    __shared__ float p_s[KB * HT];         // 1024 B  [j][h]
    __shared__ float alpha_s[HT];
    __shared__ float m_s[HT];
    __shared__ float l_s[HT];
    __shared__ int   rows_s[KB];
    // total ~79.6 KB -> 2 blocks/CU

    // XCD swizzle: all 8 head-tiles of one (b,sp) share blockIdx%8 -> same XCD L2
    const int pblk  = blockIdx.x;
    const int xcd   = pblk & 7;
    const int htile = (pblk >> 3) & 7;
    const int bs    = ((pblk >> 6) << 3) + xcd;   // 0..255 = b*NS + sp
    const int b     = bs >> 3;
    const int sp    = bs & 7;
    const int h0    = htile * HT;

    const int t    = threadIdx.x;
    const int wave = t >> 6;
    const int lane = t & 63;

    const int seq   = indptr[b + 1] - indptr[b];
    const int klps  = (seq + NS_ - 1) / NS_;
    const int start = sp * klps;
    const int end   = min(start + klps, seq);

    // stage q tile (16 heads x 576 floats), padded pitch
    {
        const float4* qg = (const float4*)(q + (size_t)(b * H_ + h0) * D_);
        #pragma unroll
        for (int i = 0; i < 9; ++i) {
            int g   = t + 256 * i;           // 0..2303 float4s
            int row = g / 144;
            int col = g - row * 144;
            *((float4*)(q_s + row * PITCH) + col) = qg[g];
        }
    }
    if (t < HT) { m_s[t] = -INFINITY; l_s[t] = 0.f; }

    float2 acc[HT];
    #pragma unroll
    for (int h = 0; h < HT; ++h) { acc[h].x = 0.f; acc[h].y = 0.f; }

    const int   c0       = wave * 128 + lane * 2;   // this thread's output c-pair
    const float sm_scale = 1.0f / sqrtf((float)D_);

    const int nchunk = (end - start + KB - 1) / KB;

    for (int ch = 0; ch < nchunk; ++ch) {
        const int j0 = start + ch * KB;

        // ---- stage K chunk: 16 rows x 576 floats (gathered via kv_indices) ----
        {
            const int row = t >> 4;
            const int fi  = t & 15;
            int pos  = j0 + row;
            int posc = min(pos, end - 1);            // clamp: masked later
            int r    = indices[b * S_ + posc];
            if (fi == 0) rows_s[row] = r;
            const float4* src = (const float4*)(kbuf + (size_t)r * D_);
            float4* dst = (float4*)(k_s + row * PITCH);
            #pragma unroll
            for (int i = 0; i < 9; ++i) dst[fi + 16 * i] = src[fi + 16 * i];
        }
        __syncthreads();

        // ---- preload this wave's V slice to regs; latency hides under scores ----
        float2 v2[KB];
        #pragma unroll
        for (int j = 0; j < KB; ++j)
            v2[j] = *(const float2*)(vbuf + (size_t)rows_s[j] * C_ + c0);

        // ---- partial scores: wave owns d-range [wave*144, wave*144+144) ----
        {
            const int hg = lane >> 4;   // 4 head-groups of 4 heads
            const int pg = lane & 15;   // 16 kv positions
            float s0 = 0.f, s1 = 0.f, s2 = 0.f, s3 = 0.f;
            const float4* kp = (const float4*)(k_s + pg * PITCH + wave * 144);
            const float4* q0 = (const float4*)(q_s + (4 * hg + 0) * PITCH + wave * 144);
            const float4* q1 = (const float4*)(q_s + (4 * hg + 1) * PITCH + wave * 144);
            const float4* q2 = (const float4*)(q_s + (4 * hg + 2) * PITCH + wave * 144);
            const float4* q3 = (const float4*)(q_s + (4 * hg + 3) * PITCH + wave * 144);
            #pragma unroll 6
            for (int dd = 0; dd < 36; ++dd) {
                float4 kv = kp[dd];
                float4 qa;
                qa = q0[dd];
                s0 = fmaf(qa.x, kv.x, s0); s0 = fmaf(qa.y, kv.y, s0);
                s0 = fmaf(qa.z, kv.z, s0); s0 = fmaf(qa.w, kv.w, s0);
                qa = q1[dd];
                s1 = fmaf(qa.x, kv.x, s1); s1 = fmaf(qa.y, kv.y, s1);
                s1 = fmaf(qa.z, kv.z, s1); s1 = fmaf(qa.w, kv.w, s1);
                qa = q2[dd];
                s2 = fmaf(qa.x, kv.x, s2); s2 = fmaf(qa.y, kv.y, s2);
                s2 = fmaf(qa.z, kv.z, s2); s2 = fmaf(qa.w, kv.w, s2);
                qa = q3[dd];
                s3 = fmaf(qa.x, kv.x, s3); s3 = fmaf(qa.y, kv.y, s3);
                s3 = fmaf(qa.z, kv.z, s3); s3 = fmaf(qa.w, kv.w, s3);
            }
            s_part[wave * 256 + (4 * hg + 0) * KB + pg] = s0;
            s_part[wave * 256 + (4 * hg + 1) * KB + pg] = s1;
            s_part[wave * 256 + (4 * hg + 2) * KB + pg] = s2;
            s_part[wave * 256 + (4 * hg + 3) * KB + pg] = s3;
        }
        __syncthreads();

        // ---- online softmax update: thread t -> (h = t>>4, j = t&15) ----
        {
            const int h = t >> 4;
            const int j = t & 15;
            float s = (s_part[t] + s_part[256 + t] + s_part[512 + t] + s_part[768 + t]) * sm_scale;
            const bool valid = (j0 + j) < end;
            if (!valid) s = -INFINITY;
            float mc = s;
            mc = fmaxf(mc, __shfl_xor(mc, 1, 16));
            mc = fmaxf(mc, __shfl_xor(mc, 2, 16));
            mc = fmaxf(mc, __shfl_xor(mc, 4, 16));
            mc = fmaxf(mc, __shfl_xor(mc, 8, 16));
            const float m_old = m_s[h];
            const float m_new = fmaxf(m_old, mc);
            float pv = valid ? __expf(s - m_new) : 0.f;
            float ps = pv;
            ps += __shfl_xor(ps, 1, 16);
            ps += __shfl_xor(ps, 2, 16);
            ps += __shfl_xor(ps, 4, 16);
            ps += __shfl_xor(ps, 8, 16);
            p_s[j * HT + h] = pv;
            if (j == 0) {
                const float al = __expf(m_old - m_new);  // m_old=-inf -> al=0
                alpha_s[h] = al;
                l_s[h] = l_s[h] * al + ps;
                m_s[h] = m_new;
            }
        }
        __syncthreads();

        // ---- PV accumulate: wave owns c-range [wave*128, wave*128+128) ----
        {
            #pragma unroll
            for (int h = 0; h < HT; ++h) {
                const float al = alpha_s[h];
                acc[h].x *= al; acc[h].y *= al;
            }
            #pragma unroll 4
            for (int j = 0; j < KB; ++j) {
                const float4 pa = *(const float4*)(p_s + j * HT + 0);
                const float4 pb = *(const float4*)(p_s + j * HT + 4);
                const float4 pc = *(const float4*)(p_s + j * HT + 8);
                const float4 pd = *(const float4*)(p_s + j * HT + 12);
                const float2 v  = v2[j];
#define PVH(idx, w) { acc[idx].x = fmaf((w), v.x, acc[idx].x); acc[idx].y = fmaf((w), v.y, acc[idx].y); }
                PVH(0,  pa.x) PVH(1,  pa.y) PVH(2,  pa.z) PVH(3,  pa.w)
                PVH(4,  pb.x) PVH(5,  pb.y) PVH(6,  pb.z) PVH(7,  pb.w)
                PVH(8,  pc.x) PVH(9,  pc.y) PVH(10, pc.z) PVH(11, pc.w)
                PVH(12, pd.x) PVH(13, pd.y) PVH(14, pd.z) PVH(15, pd.w)
#undef PVH
            }
        }
        __syncthreads();
    }

    // ---- epilogue: o = acc / l, lse = m + log(l) ----
    #pragma unroll
    for (int h = 0; h < HT; ++h) {
        const float inv = 1.0f / l_s[h];
        float* op = out + (size_t)((b * H_ + h0 + h) * NS_ + sp) * (C_ + 1) + c0;
        op[0] = acc[h].x * inv;
        op[1] = acc[h].y * inv;
    }
    if (t < HT) {
        out[(size_t)((b * H_ + h0 + t) * NS_ + sp) * (C_ + 1) + C_] = m_s[t] + logf(l_s[t]);
    }
}

// ---------------- launcher --------------------------------------------------

extern "C" void kernel_launch(void* const* d_in, const int* in_sizes, int n_in,
                              void* d_out, int out_size, void* d_ws, size_t ws_size,
                              hipStream_t stream) {
    float*       qp        = (float*)d_in[0];
    float*       kbuf      = (float*)d_in[1];
    const float* vbuf      = (const float*)d_in[2];
    const float* cache     = (const float*)d_in[3];
    const int*   positions = (const int*)d_in[4];
    const int*   indptr    = (const int*)d_in[5];
    const int*   indices   = (const int*)d_in[6];
    float*       out       = (float*)d_out;

    const long long tail = (long long)B_ * H_ * NS_ * (C_ + 1);
    const bool use_rope = ((long long)out_size == tail + (long long)B_ * R_);

    if (use_rope) {
        rope_q_kernel<<<(B_ * H_ * HALF_ + 255) / 256, 256, 0, stream>>>(qp, cache, positions);
        rope_k_kernel<<<(B_ * HALF_ + 255) / 256, 256, 0, stream>>>(
            kbuf, cache, positions, indptr, indices, out + tail);
    } else {
        zero_tail_kernel<<<1, 64, 0, stream>>>(out + tail);
    }

    mla_attn_kernel<<<dim3(2048), dim3(256), 0, stream>>>(qp, kbuf, vbuf, indptr, indices, out);
}

// Round 3
// 803.039 us; speedup vs baseline: 2.1255x; 2.1255x over previous
//
#include <hip/hip_runtime.h>
#include <math.h>

#define B_    32
#define H_    128
#define C_    512
#define R_    64
#define S_    4096
#define NS_   8
#define D_    576      // C_ + R_
#define HALF_ 32
#define HT    32       // heads per block
#define KB    32       // kv positions per chunk
#define PK    584      // k_lds pitch (halfs): 1168 B rows, granule-pitch 73 (odd) -> uniform banks
#define PS    36       // s_lds pitch (floats)
#define PP    40       // p_lds pitch (halfs)

typedef _Float16 half8   __attribute__((ext_vector_type(8)));
typedef _Float16 half4_t __attribute__((ext_vector_type(4)));
typedef float    f32x4   __attribute__((ext_vector_type(4)));

// ---------------- RoPE kernels (in-place; harness restores inputs pre-launch) --

__global__ __launch_bounds__(256)
void rope_q_kernel(float* __restrict__ q, const float* __restrict__ cache,
                   const int* __restrict__ positions) {
    int t = blockIdx.x * 256 + threadIdx.x;
    if (t >= B_ * H_ * HALF_) return;
    int i = t & (HALF_ - 1);
    int h = (t >> 5) & (H_ - 1);
    int b = t >> 12;
    int pos = positions[b];
    float c = cache[pos * R_ + i];
    float s = cache[pos * R_ + HALF_ + i];
    float* qp = q + (size_t)(b * H_ + h) * D_ + C_;
    float lo = qp[i], hi = qp[i + HALF_];
    qp[i]         = lo * c - hi * s;
    qp[i + HALF_] = hi * c + lo * s;
}

__global__ __launch_bounds__(256)
void rope_k_kernel(float* __restrict__ kbuf, const float* __restrict__ cache,
                   const int* __restrict__ positions, const int* __restrict__ indptr,
                   const int* __restrict__ indices, float* __restrict__ out_tail) {
    int t = blockIdx.x * 256 + threadIdx.x;
    if (t >= B_ * HALF_) return;
    int i = t & (HALF_ - 1);
    int b = t >> 5;
    int seq = indptr[b + 1] - indptr[b];
    int row = indices[b * S_ + seq - 1];
    int pos = positions[b];
    float c = cache[pos * R_ + i];
    float s = cache[pos * R_ + HALF_ + i];
    float* kp = kbuf + (size_t)row * D_ + C_;
    float lo = kp[i], hi = kp[i + HALF_];
    float nlo = lo * c - hi * s;
    float nhi = hi * c + lo * s;
    kp[i] = nlo; kp[i + HALF_] = nhi;
    out_tail[b * R_ + i]         = nlo;
    out_tail[b * R_ + HALF_ + i] = nhi;
}

__global__ void zero_tail_kernel(float* p) { if (threadIdx.x == 0) p[0] = 0.f; }

// ---------------- fused split attention, fp16 MFMA ---------------------------

__global__ __launch_bounds__(256, 2)
void mla_attn_kernel(const float* __restrict__ q, const float* __restrict__ kbuf,
                     const float* __restrict__ vbuf, const int* __restrict__ indptr,
                     const int* __restrict__ indices, float* __restrict__ out) {
    __shared__ _Float16 k_lds[KB * PK];   // 37376 B
    __shared__ float    s_lds[HT * PS];   //  4608 B
    __shared__ _Float16 p_lds[HT * PP];   //  2560 B
    __shared__ int      rows_s[KB];
    __shared__ float    m_s[HT], l_s[HT], a_s[HT];

    // XCD swizzle: 4 head-tiles of one (b,sp) share blockIdx%8 -> same XCD L2
    const int blk   = blockIdx.x;
    const int xcd   = blk & 7;
    const int inner = blk >> 3;          // 0..127
    const int htile = inner & 3;
    const int bs    = ((inner >> 2) << 3) | xcd;  // 0..255 = b*NS + sp
    const int b     = bs >> 3;
    const int sp    = bs & 7;
    const int h0    = htile * HT;

    const int t    = threadIdx.x;
    const int lane = t & 63;
    const int w    = t >> 6;
    const int hm   = w >> 1;   // head sub-tile (16 heads)
    const int hv   = w & 1;    // scores: kv sub-tile; PV: c-half
    const int lr   = lane & 15;
    const int kg   = lane >> 4;

    const int seq   = indptr[b + 1] - indptr[b];
    const int klps  = (seq + NS_ - 1) / NS_;
    const int start = sp * klps;
    const int end   = min(start + klps, seq);

    // ---- Q A-fragments in registers: 16 heads x 576, fp16 ----
    half8 qf[18];
    {
        const float* qrow = q + (size_t)(b * H_ + h0 + hm * 16 + lr) * D_ + kg * 8;
        #pragma unroll
        for (int s = 0; s < 18; ++s) {
            f32x4 x0 = *(const f32x4*)(qrow + s * 32);
            f32x4 x1 = *(const f32x4*)(qrow + s * 32 + 4);
            half8 h;
            h[0] = (_Float16)x0[0]; h[1] = (_Float16)x0[1];
            h[2] = (_Float16)x0[2]; h[3] = (_Float16)x0[3];
            h[4] = (_Float16)x1[0]; h[5] = (_Float16)x1[1];
            h[6] = (_Float16)x1[2]; h[7] = (_Float16)x1[3];
            qf[s] = h;
        }
    }
    if (t < HT) { m_s[t] = -INFINITY; l_s[t] = 0.f; }

    f32x4 oacc[16];
    #pragma unroll
    for (int n = 0; n < 16; ++n) oacc[n] = (f32x4){0.f, 0.f, 0.f, 0.f};

    const float sm_scale = 1.0f / sqrtf((float)D_);
    const int nchunk = (end - start + KB - 1) / KB;

    for (int ch = 0; ch < nchunk; ++ch) {
        const int j0 = start + ch * KB;
        __syncthreads();   // prev PV done before restaging k_lds / rows_s

        // ---- stage K chunk: 32 rows x 576, fp32 global -> fp16 LDS ----
        {
            const int row = t >> 3;
            const int seg = t & 7;
            const int pos = min(j0 + row, end - 1);
            const int r   = indices[b * S_ + pos];
            if (seg == 0) rows_s[row] = r;
            const float* src = kbuf + (size_t)r * D_;
            _Float16* dst = k_lds + row * PK;
            #pragma unroll
            for (int i = 0; i < 18; ++i) {
                const int f = (seg + 8 * i) * 4;
                f32x4 x = *(const f32x4*)(src + f);
                half4_t hh;
                hh[0] = (_Float16)x[0]; hh[1] = (_Float16)x[1];
                hh[2] = (_Float16)x[2]; hh[3] = (_Float16)x[3];
                *(half4_t*)(dst + f) = hh;
            }
        }
        __syncthreads();

        // ---- scores: wave computes 16h x 16kv tile (hm, hv), K=576 ----
        {
            f32x4 sacc = (f32x4){0.f, 0.f, 0.f, 0.f};
            const _Float16* kp = k_lds + (hv * 16 + lr) * PK + kg * 8;
            #pragma unroll
            for (int s = 0; s < 18; ++s) {
                half8 bf = *(const half8*)(kp + s * 32);
                sacc = __builtin_amdgcn_mfma_f32_16x16x32_f16(qf[s], bf, sacc, 0, 0, 0);
            }
            #pragma unroll
            for (int r = 0; r < 4; ++r)
                s_lds[(hm * 16 + kg * 4 + r) * PS + hv * 16 + lr] = sacc[r] * sm_scale;
        }
        __syncthreads();

        // ---- online softmax: 8 threads per head, 4 kv each ----
        {
            const int h  = t >> 3;
            const int j8 = t & 7;
            f32x4 s4 = *(const f32x4*)(s_lds + h * PS + j8 * 4);
            const int jb = j0 + j8 * 4;
            if (jb + 0 >= end) s4[0] = -INFINITY;
            if (jb + 1 >= end) s4[1] = -INFINITY;
            if (jb + 2 >= end) s4[2] = -INFINITY;
            if (jb + 3 >= end) s4[3] = -INFINITY;
            float mx = fmaxf(fmaxf(s4[0], s4[1]), fmaxf(s4[2], s4[3]));
            mx = fmaxf(mx, __shfl_xor(mx, 1, 8));
            mx = fmaxf(mx, __shfl_xor(mx, 2, 8));
            mx = fmaxf(mx, __shfl_xor(mx, 4, 8));
            const float m_old = m_s[h];
            const float m_new = fmaxf(m_old, mx);
            float p0 = (jb + 0 < end) ? __expf(s4[0] - m_new) : 0.f;
            float p1 = (jb + 1 < end) ? __expf(s4[1] - m_new) : 0.f;
            float p2 = (jb + 2 < end) ? __expf(s4[2] - m_new) : 0.f;
            float p3 = (jb + 3 < end) ? __expf(s4[3] - m_new) : 0.f;
            float ps = p0 + p1 + p2 + p3;
            ps += __shfl_xor(ps, 1, 8);
            ps += __shfl_xor(ps, 2, 8);
            ps += __shfl_xor(ps, 4, 8);
            half4_t ph;
            ph[0] = (_Float16)p0; ph[1] = (_Float16)p1;
            ph[2] = (_Float16)p2; ph[3] = (_Float16)p3;
            *(half4_t*)(p_lds + h * PP + j8 * 4) = ph;
            if (j8 == 0) {
                const float al = __expf(m_old - m_new);   // -inf -> 0
                a_s[h] = al;
                l_s[h] = l_s[h] * al + ps;
                m_s[h] = m_new;
            }
        }
        __syncthreads();

        // ---- PV: wave (hm, hv) -> 16 heads x 256 c-channels, K=32 ----
        {
            const float* vp[8];
            #pragma unroll
            for (int j = 0; j < 8; ++j)
                vp[j] = vbuf + (size_t)rows_s[kg * 8 + j] * C_ + hv * 256 + lr;
            half8 pf = *(const half8*)(p_lds + (hm * 16 + lr) * PP + kg * 8);
            float av[4];
            #pragma unroll
            for (int r = 0; r < 4; ++r) av[r] = a_s[hm * 16 + kg * 4 + r];
            #pragma unroll
            for (int n = 0; n < 16; ++n) {
                oacc[n][0] *= av[0]; oacc[n][1] *= av[1];
                oacc[n][2] *= av[2]; oacc[n][3] *= av[3];
            }
            #pragma unroll
            for (int n = 0; n < 16; ++n) {
                half8 vf;
                #pragma unroll
                for (int j = 0; j < 8; ++j)
                    vf[j] = (_Float16)vp[j][n * 16];
                oacc[n] = __builtin_amdgcn_mfma_f32_16x16x32_f16(pf, vf, oacc[n], 0, 0, 0);
            }
        }
    }

    // ---- epilogue: o = acc/l, lse = m + log(l) ----
    {
        float inv[4];
        #pragma unroll
        for (int r = 0; r < 4; ++r) inv[r] = 1.0f / l_s[hm * 16 + kg * 4 + r];
        #pragma unroll
        for (int n = 0; n < 16; ++n) {
            #pragma unroll
            for (int r = 0; r < 4; ++r) {
                const int h = h0 + hm * 16 + kg * 4 + r;
                out[(size_t)((b * H_ + h) * NS_ + sp) * (C_ + 1) + hv * 256 + n * 16 + lr]
                    = oacc[n][r] * inv[r];
            }
        }
        if (t < HT)
            out[(size_t)((b * H_ + h0 + t) * NS_ + sp) * (C_ + 1) + C_]
                = m_s[t] + logf(l_s[t]);
    }
}

// ---------------- launcher --------------------------------------------------

extern "C" void kernel_launch(void* const* d_in, const int* in_sizes, int n_in,
                              void* d_out, int out_size, void* d_ws, size_t ws_size,
                              hipStream_t stream) {
    float*       qp        = (float*)d_in[0];
    float*       kbuf      = (float*)d_in[1];
    const float* vbuf      = (const float*)d_in[2];
    const float* cache     = (const float*)d_in[3];
    const int*   positions = (const int*)d_in[4];
    const int*   indptr    = (const int*)d_in[5];
    const int*   indices   = (const int*)d_in[6];
    float*       out       = (float*)d_out;

    const long long tail = (long long)B_ * H_ * NS_ * (C_ + 1);
    const bool use_rope = ((long long)out_size == tail + (long long)B_ * R_);

    if (use_rope) {
        rope_q_kernel<<<(B_ * H_ * HALF_ + 255) / 256, 256, 0, stream>>>(qp, cache, positions);
        rope_k_kernel<<<(B_ * HALF_ + 255) / 256, 256, 0, stream>>>(
            kbuf, cache, positions, indptr, indices, out + tail);
    } else {
        zero_tail_kernel<<<1, 64, 0, stream>>>(out + tail);
    }

    mla_attn_kernel<<<dim3(1024), dim3(256), 0, stream>>>(qp, kbuf, vbuf, indptr, indices, out);
}